// Round 6
// baseline (317.641 us; speedup 1.0000x reference)
//
#include <hip/hip_runtime.h>

#define N_NODES   100000
#define N_EDGES   1600000
#define N_GRAPHS  128
#define HIDDEN    128
#define N_CLASSES 10

#define BSH   8                   // bucket = 256 nodes
#define BSZ   256
#define NBUCK 391                 // ceil(100000/256)
#define NPAD  (NBUCK * BSZ)       // 100096
#define NBIN  512                 // histogram bins (>= NBUCK), == PTH
#define CAP   8192                // mean fill 4096, 2x headroom
#define PCH   2048                // edges per partition block (782 blocks)
#define PTH   512                 // partition threads
#define PIT   (PCH / PTH)         // 4
#define SPLIT 4                   // sub-blocks per bucket in edge kernels

typedef unsigned int   uint;
typedef unsigned short ushort;
typedef unsigned char  uchar;

// ---- 512-wide exclusive scan: wave shfl scan + tiny cross-wave fixup (2 syncs)
__device__ __forceinline__ uint scan_excl_512(uint v, int t, uint* wtmp) {
    uint lane = (uint)(t & 63);
    uint incl = v;
    #pragma unroll
    for (int off = 1; off < 64; off <<= 1) {
        uint up = __shfl_up(incl, off, 64);
        if (lane >= (uint)off) incl += up;
    }
    if (lane == 63) wtmp[t >> 6] = incl;
    __syncthreads();
    uint wo = 0;
    int w = t >> 6;
    #pragma unroll
    for (int k = 0; k < 7; ++k) wo += (k < w) ? wtmp[k] : 0u;
    __syncthreads();
    return incl + wo - v;
}

// -------- partition (R3-verified structure; PCH=2048, uchar tmp2) ------------
__global__ __launch_bounds__(PTH)
void k_part(const int* __restrict__ src, const int* __restrict__ dst,
            uint* __restrict__ bcur1, uint* __restrict__ bcur2,
            uint* __restrict__ tmp1, uchar* __restrict__ tmp2, int nE) {
    __shared__ uint   hist[NBIN], lcur[NBIN], base[NBIN];   // 6 KB
    __shared__ uint   wtmp[8];
    __shared__ uint   stag4[PCH];        // 8 KB
    __shared__ ushort stagB[PCH];        // 4 KB (phase 1 only)
    int t = threadIdx.x;
    int e0 = blockIdx.x * PCH;
    int e1 = min(e0 + PCH, nE);
    int cntE = e1 - e0;

    int sv[PIT], dv[PIT];
    // ---------------- phase 1: dst ----------------
    hist[t] = 0;                         // NBIN == PTH
    __syncthreads();
    #pragma unroll
    for (int m = 0; m < PIT; ++m) {
        int e = e0 + t + m * PTH;
        if (e < e1) {
            sv[m] = src[e]; dv[m] = dst[e];
            atomicAdd(&hist[dv[m] >> BSH], 1u);
        }
    }
    __syncthreads();
    uint v = hist[t];
    uint excl = scan_excl_512(v, t, wtmp);
    lcur[t] = excl;
    if (v > 0) { uint g = atomicAdd(&bcur1[t], v); base[t] = (uint)t * CAP + g - excl; }
    __syncthreads();
    #pragma unroll
    for (int m = 0; m < PIT; ++m) {
        int e = e0 + t + m * PTH;
        if (e < e1) {
            int d = dv[m], s = sv[m];
            int b = d >> BSH;
            uint p = atomicAdd(&lcur[b], 1u);
            stag4[p] = ((uint)(d & (BSZ - 1)) << 17) | (uint)s;
            stagB[p] = (ushort)b;
        }
    }
    __syncthreads();
    for (int i = t; i < cntE; i += PTH) {
        uint b = stagB[i];
        uint a = base[b] + (uint)i;
        if (a < (b + 1u) * CAP) tmp1[a] = stag4[i];
    }
    __syncthreads();

    // ---------------- phase 2: src ----------------
    hist[t] = 0;
    __syncthreads();
    #pragma unroll
    for (int m = 0; m < PIT; ++m) {
        int e = e0 + t + m * PTH;
        if (e < e1) atomicAdd(&hist[sv[m] >> BSH], 1u);
    }
    __syncthreads();
    v = hist[t];
    excl = scan_excl_512(v, t, wtmp);
    lcur[t] = excl;
    if (v > 0) { uint g = atomicAdd(&bcur2[t], v); base[t] = (uint)t * CAP + g - excl; }
    __syncthreads();
    #pragma unroll
    for (int m = 0; m < PIT; ++m) {
        int e = e0 + t + m * PTH;
        if (e < e1) {
            int s = sv[m];
            uint p = atomicAdd(&lcur[s >> BSH], 1u);
            stag4[p] = (uint)s;
        }
    }
    __syncthreads();
    for (int i = t; i < cntE; i += PTH) {
        uint s = stag4[i];
        uint b = s >> BSH;
        uint a = base[b] + (uint)i;
        if (a < (b + 1u) * CAP) tmp2[a] = (uchar)(s & (BSZ - 1));
    }
}

// ------- degrees: (bucket, quarter) split blocks, coalesced atomic merge,
//         last ticket-holder finishes node pass (ns/hs0/ndv). UV table on q==0,b<129.
__global__ __launch_bounds__(256)
void k_deg(const uint* __restrict__ bcur1, const uint* __restrict__ tmp1,
           const uint* __restrict__ bcur2, const uchar* __restrict__ tmp2,
           const float* __restrict__ W1, const float* __restrict__ b1,
           const float* __restrict__ W2,
           uint* __restrict__ cin, uint* __restrict__ cout, uint* __restrict__ tick,
           float* __restrict__ ns, float* __restrict__ hs0, float* __restrict__ ndv,
           float* __restrict__ U, float* __restrict__ V) {
    __shared__ uint  lin[BSZ], lout[BSZ];
    __shared__ float sts[128];
    __shared__ uint  sdone;
    int bid = blockIdx.x;
    int b = bid >> 2, q = bid & 3;
    int t = threadIdx.x;
    lin[t] = 0; lout[t] = 0;
    __syncthreads();

    bool uvblk = (q == 0 && b < 129);     // block-uniform: interior syncs legal
    if (uvblk) {
        if (t < 128) {
            float w = W1[t], bb = b1[t];
            sts[t] = (w != 0.0f) ? (-bb / w) : 1e30f;
        }
        __syncthreads();
        for (int k = 2; k <= 128; k <<= 1) {
            for (int j = k >> 1; j > 0; j >>= 1) {
                if (t < 128) {
                    int ixj = t ^ j;
                    if (ixj > t) {
                        float a = sts[t], bb = sts[ixj];
                        bool up = ((t & k) == 0);
                        if (up ? (a > bb) : (a < bb)) { sts[t] = bb; sts[ixj] = a; }
                    }
                }
                __syncthreads();
            }
        }
        if (t < 128) {
            int sg = b;
            float a_rep;
            if (sg == 0)        a_rep = sts[0]   - 1.0f;
            else if (sg == 128) a_rep = sts[127] + 1.0f;
            else                a_rep = 0.5f * (sts[sg - 1] + sts[sg]);
            float u = 0.0f, vv = 0.0f;
            #pragma unroll 8
            for (int j = 0; j < 128; ++j) {
                float w  = W1[j], bb = b1[j];
                float w2 = W2[j * HIDDEN + t];
                bool on  = (a_rep * w + bb > 0.0f);
                u  += on ? w  * w2 : 0.0f;
                vv += on ? bb * w2 : 0.0f;
            }
            U[sg * HIDDEN + t] = u;
            V[sg * HIDDEN + t] = vv;
        }
    }

    // quarter of tmp1 -> lin
    uint f1 = min(bcur1[b], (uint)CAP);
    uint lo = f1 * (uint)q / 4u, hi = f1 * (uint)(q + 1) / 4u;
    const uint* tp1 = tmp1 + (size_t)b * CAP;
    uint i = lo + t;
    for (; i + 768u < hi; i += 1024u) {
        uint a0 = tp1[i], a1 = tp1[i + 256], a2 = tp1[i + 512], a3 = tp1[i + 768];
        atomicAdd(&lin[a0 >> 17], 1u); atomicAdd(&lin[a1 >> 17], 1u);
        atomicAdd(&lin[a2 >> 17], 1u); atomicAdd(&lin[a3 >> 17], 1u);
    }
    for (; i < hi; i += 256u) atomicAdd(&lin[tp1[i] >> 17], 1u);

    // quarter of tmp2 (word-packed) -> lout
    uint f2 = min(bcur2[b], (uint)CAP);
    const uchar* tp2 = tmp2 + (size_t)b * CAP;
    const uint* tp2w = (const uint*)tp2;         // CAP-aligned
    uint nw = f2 >> 2;
    uint wlo = nw * (uint)q / 4u, whi = nw * (uint)(q + 1) / 4u;
    for (i = wlo + t; i < whi; i += 256u) {
        uint w4 = tp2w[i];
        atomicAdd(&lout[w4 & 255u], 1u);
        atomicAdd(&lout[(w4 >> 8) & 255u], 1u);
        atomicAdd(&lout[(w4 >> 16) & 255u], 1u);
        atomicAdd(&lout[(w4 >> 24) & 255u], 1u);
    }
    if (q == 3) for (i = (nw << 2) + t; i < f2; i += 256u) atomicAdd(&lout[tp2[i]], 1u);
    __syncthreads();

    int n = b * BSZ + t;
    atomicAdd(&cin[n],  lin[t]);          // coalesced device atomics
    atomicAdd(&cout[n], lout[t]);
    __syncthreads();                       // drains each thread's vmcnt pre-barrier
    if (t == 0) sdone = __hip_atomic_fetch_add(&tick[b], 1u, __ATOMIC_ACQ_REL,
                                               __HIP_MEMORY_SCOPE_AGENT);
    __syncthreads();
    if (sdone == SPLIT - 1) {              // last block: node finish
        if (n < N_NODES) {
            uint ci = cin[n];
            uint co = cout[n];
            float nsv = rsqrtf(fmaxf((float)co, 1.0f));
            ns[n]  = nsv;
            hs0[n] = (float)ci * nsv;
            ndv[n] = rsqrtf(fmaxf((float)ci, 1.0f));
        }
    }
}

// ------- conv1 aggregation: split blocks + atomic merge; last block emits info
__global__ __launch_bounds__(256)
void k_agg1(const uint* __restrict__ bcur1, const uint* __restrict__ tmp1,
            const float* __restrict__ hs0, const float* __restrict__ ns,
            const float* __restrict__ ndv,
            const float* __restrict__ W1, const float* __restrict__ b1,
            float* __restrict__ aggC, uint* __restrict__ tick,
            float4* __restrict__ info) {
    __shared__ float agg[BSZ];
    __shared__ float stu[128];
    __shared__ uint  sdone;
    int bid = blockIdx.x;
    int b = bid >> 2, q = bid & 3;
    int t = threadIdx.x;
    agg[t] = 0.0f;
    if (t < 128) {
        float w = W1[t], bb = b1[t];
        stu[t] = (w != 0.0f) ? (-bb / w) : 1e30f;
    }
    __syncthreads();
    uint f1 = min(bcur1[b], (uint)CAP);
    uint lo = f1 * (uint)q / 4u, hi = f1 * (uint)(q + 1) / 4u;
    const uint* tp1 = tmp1 + (size_t)b * CAP;
    uint i = lo + t;
    for (; i + 768u < hi; i += 1024u) {
        uint e0 = tp1[i], e1 = tp1[i + 256], e2 = tp1[i + 512], e3 = tp1[i + 768];
        float h0 = hs0[e0 & 0x1FFFFu], h1 = hs0[e1 & 0x1FFFFu];
        float h2 = hs0[e2 & 0x1FFFFu], h3 = hs0[e3 & 0x1FFFFu];
        atomicAdd(&agg[e0 >> 17], h0); atomicAdd(&agg[e1 >> 17], h1);
        atomicAdd(&agg[e2 >> 17], h2); atomicAdd(&agg[e3 >> 17], h3);
    }
    for (; i < hi; i += 256u) {
        uint e = tp1[i];
        atomicAdd(&agg[e >> 17], hs0[e & 0x1FFFFu]);
    }
    __syncthreads();
    int n = b * BSZ + t;
    atomicAdd(&aggC[n], agg[t]);
    __syncthreads();
    if (t == 0) sdone = __hip_atomic_fetch_add(&tick[b], 1u, __ATOMIC_ACQ_REL,
                                               __HIP_MEMORY_SCOPE_AGENT);
    __syncthreads();
    if (sdone == SPLIT - 1) {
        if (n < N_NODES) {
            float nd = ndv[n];
            float av = aggC[n] * nd;
            int sgp = 0;
            #pragma unroll 16
            for (int qq = 0; qq < 128; ++qq) sgp += (stu[qq] < av) ? 1 : 0;
            float nsv = ns[n];
            info[n] = make_float4(nsv * av, nsv, __int_as_float(sgp), nd);
        }
    }
}

// ------- conv2 aggregation: split blocks + atomic merge; last block does
//         rows + pooling; very last bucket computes the classifier head.
__global__ __launch_bounds__(256)
void k_agg2(const uint* __restrict__ bcur1, const uint* __restrict__ tmp1,
            const float4* __restrict__ info, const float* __restrict__ ndv,
            float* __restrict__ aggA, float* __restrict__ aggB,
            uint* __restrict__ aggMnI, uint* __restrict__ aggMx,
            uint* __restrict__ tick, uint* __restrict__ tickF,
            const float* __restrict__ U, const float* __restrict__ V,
            const int* __restrict__ graph_ids, const float* __restrict__ b2,
            float* __restrict__ pool, float* __restrict__ cnt,
            const float* __restrict__ Wc, const float* __restrict__ bc,
            float* __restrict__ out) {
    __shared__ float lA[BSZ], lB[BSZ];
    __shared__ uint  lmn[BSZ], lmx[BSZ];
    __shared__ float sWc[HIDDEN * N_CLASSES];
    __shared__ float sbc[N_CLASSES];
    __shared__ uint  sdone, sdone2;
    int bid = blockIdx.x;
    int b = bid >> 2, q = bid & 3;
    int t = threadIdx.x;
    lA[t] = 0.0f; lB[t] = 0.0f; lmn[t] = 255u; lmx[t] = 0u;
    __syncthreads();
    uint f1 = min(bcur1[b], (uint)CAP);
    uint lo = f1 * (uint)q / 4u, hi = f1 * (uint)(q + 1) / 4u;
    const uint* tp1 = tmp1 + (size_t)b * CAP;
    uint i = lo + t;
    for (; i + 768u < hi; i += 1024u) {
        uint e0 = tp1[i], e1 = tp1[i + 256], e2 = tp1[i + 512], e3 = tp1[i + 768];
        float4 n0 = info[e0 & 0x1FFFFu];
        float4 n1 = info[e1 & 0x1FFFFu];
        float4 n2 = info[e2 & 0x1FFFFu];
        float4 n3 = info[e3 & 0x1FFFFu];
        uint d0 = e0 >> 17, d1 = e1 >> 17, d2 = e2 >> 17, d3 = e3 >> 17;
        atomicAdd(&lA[d0], n0.x); atomicAdd(&lB[d0], n0.y);
        atomicAdd(&lA[d1], n1.x); atomicAdd(&lB[d1], n1.y);
        atomicAdd(&lA[d2], n2.x); atomicAdd(&lB[d2], n2.y);
        atomicAdd(&lA[d3], n3.x); atomicAdd(&lB[d3], n3.y);
        uint s0 = (uint)__float_as_int(n0.z), s1 = (uint)__float_as_int(n1.z);
        uint s2 = (uint)__float_as_int(n2.z), s3 = (uint)__float_as_int(n3.z);
        atomicMin(&lmn[d0], s0); atomicMax(&lmx[d0], s0);
        atomicMin(&lmn[d1], s1); atomicMax(&lmx[d1], s1);
        atomicMin(&lmn[d2], s2); atomicMax(&lmx[d2], s2);
        atomicMin(&lmn[d3], s3); atomicMax(&lmx[d3], s3);
    }
    for (; i < hi; i += 256u) {
        uint e = tp1[i];
        uint dl = e >> 17;
        float4 nf = info[e & 0x1FFFFu];
        atomicAdd(&lA[dl], nf.x);
        atomicAdd(&lB[dl], nf.y);
        uint sg = (uint)__float_as_int(nf.z);
        atomicMin(&lmn[dl], sg);
        atomicMax(&lmx[dl], sg);
    }
    __syncthreads();
    int n = b * BSZ + t;
    atomicAdd(&aggA[n], lA[t]);
    atomicAdd(&aggB[n], lB[t]);
    atomicMax(&aggMnI[n], 255u - lmn[t]);   // min via inverted max (zero-init safe)
    atomicMax(&aggMx[n], lmx[t]);
    __syncthreads();
    if (t == 0) sdone = __hip_atomic_fetch_add(&tick[b], 1u, __ATOMIC_ACQ_REL,
                                               __HIP_MEMORY_SCOPE_AGENT);
    __syncthreads();
    if (sdone != SPLIT - 1) return;

    // ---- finish: rows + pooling for bucket b (2 node-groups x 128 dims)
    int d = t & 127, j = t >> 7;
    float bbd = b2[d];
    int base = b * BSZ;
    int gcur = -1; float racc = 0.0f, cl = 0.0f;
    for (int r = j; r < BSZ; r += 2) {
        int nn = base + r;
        if (nn >= N_NODES) break;
        uint mn = 255u - aggMnI[nn], mx = aggMx[nn];
        float acc;
        if (mn >= mx) {                    // uniform segment (or no edges: A=B=0)
            uint sg = min(mn, 128u);
            acc = aggA[nn] * U[sg * HIDDEN + d] + aggB[nn] * V[sg * HIDDEN + d];
        } else {                           // mixed: exact rescan of bucket edges (rare)
            acc = 0.0f;
            for (uint k = 0; k < f1; ++k) {
                uint e = tp1[k];
                if ((e >> 17) == (uint)r) {
                    float4 nf = info[e & 0x1FFFFu];
                    uint sg = (uint)__float_as_int(nf.z);
                    acc += nf.x * U[sg * HIDDEN + d] + nf.y * V[sg * HIDDEN + d];
                }
            }
        }
        float row = fmaxf(ndv[nn] * acc + bbd, 0.0f);
        int g = graph_ids[nn];
        if (g != gcur) {
            if (gcur >= 0) {
                atomicAdd(&pool[gcur * HIDDEN + d], racc);
                if (d == 0) atomicAdd(&cnt[gcur], cl);
            }
            gcur = g; racc = 0.0f; cl = 0.0f;
        }
        racc += row; cl += 1.0f;
    }
    if (gcur >= 0) {
        atomicAdd(&pool[gcur * HIDDEN + d], racc);
        if (d == 0) atomicAdd(&cnt[gcur], cl);
    }
    __syncthreads();
    if (t == 0) sdone2 = __hip_atomic_fetch_add(tickF, 1u, __ATOMIC_ACQ_REL,
                                                __HIP_MEMORY_SCOPE_AGENT);
    __syncthreads();
    if (sdone2 != (uint)(NBUCK - 1)) return;

    // ---- very last bucket: classifier head (2 threads per graph)
    for (int s = t; s < HIDDEN * N_CLASSES; s += 256) sWc[s] = Wc[s];
    if (t < N_CLASSES) sbc[t] = bc[t];
    __syncthreads();
    int g = t >> 1, half = t & 1;
    float a[N_CLASSES];
    #pragma unroll
    for (int c = 0; c < N_CLASSES; ++c) a[c] = 0.0f;
    for (int jj = half * 64; jj < half * 64 + 64; ++jj) {
        float p = pool[g * HIDDEN + jj];
        #pragma unroll
        for (int c = 0; c < N_CLASSES; ++c) a[c] += p * sWc[jj * N_CLASSES + c];
    }
    #pragma unroll
    for (int c = 0; c < N_CLASSES; ++c) a[c] += __shfl_xor(a[c], 1);
    if (half == 0) {
        float inv = 1.0f / fmaxf(cnt[g], 1.0f);
        #pragma unroll
        for (int c = 0; c < N_CLASSES; ++c)
            out[g * N_CLASSES + c] = sbc[c] + a[c] * inv;
    }
}

extern "C" void kernel_launch(void* const* d_in, const int* in_sizes, int n_in,
                              void* d_out, int out_size, void* d_ws, size_t ws_size,
                              hipStream_t stream) {
    const int*   src       = (const int*)d_in[0];
    const int*   dst       = (const int*)d_in[1];
    const int*   graph_ids = (const int*)d_in[2];
    const float* W1        = (const float*)d_in[3];
    const float* b1        = (const float*)d_in[4];
    const float* W2        = (const float*)d_in[5];
    const float* b2        = (const float*)d_in[6];
    const float* Wc        = (const float*)d_in[7];
    const float* bc        = (const float*)d_in[8];
    float* out = (float*)d_out;

    char* ws = (char*)d_ws;
    size_t off = 0;
    auto alloc = [&](size_t elems) { void* p = ws + off; off += elems * 4; return p; };

    // --- zeroed region (single ~2.9MB memset) ---
    uint*  bcur1  = (uint*) alloc(NBIN);
    uint*  bcur2  = (uint*) alloc(NBIN);
    float* pool   = (float*)alloc(N_GRAPHS * HIDDEN);
    float* cnt    = (float*)alloc(N_GRAPHS);
    uint*  cin    = (uint*) alloc(NPAD);
    uint*  cout   = (uint*) alloc(NPAD);
    float* aggC   = (float*)alloc(NPAD);
    float* aggA   = (float*)alloc(NPAD);
    float* aggB   = (float*)alloc(NPAD);
    uint*  aggMnI = (uint*) alloc(NPAD);
    uint*  aggMx  = (uint*) alloc(NPAD);
    uint*  tick1  = (uint*) alloc(NBUCK);
    uint*  tick2  = (uint*) alloc(NBUCK);
    uint*  tick3  = (uint*) alloc(NBUCK);
    uint*  tickF  = (uint*) alloc(4);
    size_t zero_bytes = off;
    // --- non-zeroed ---
    off = (off + 15) & ~(size_t)15;                         // 16B align for float4
    float4* info = (float4*)alloc((size_t)NPAD * 4);        // 1.6 MB
    uint*   tmp1 = (uint*)  alloc((size_t)NBUCK * CAP);     // 12.8 MB
    uchar*  tmp2 = (uchar*) alloc((size_t)NBUCK * CAP / 4); // 3.2 MB
    float*  nsA  = (float*) alloc(NPAD);
    float*  hs0  = (float*) alloc(NPAD);
    float*  ndv  = (float*) alloc(NPAD);
    float*  U    = (float*) alloc(129 * HIDDEN);
    float*  V    = (float*) alloc(129 * HIDDEN);

    hipMemsetAsync(d_ws, 0, zero_bytes, stream);

    int pblocks = (N_EDGES + PCH - 1) / PCH;    // 782
    int gblocks = NBUCK * SPLIT;                // 1564

    k_part<<<pblocks, PTH, 0, stream>>>(src, dst, bcur1, bcur2, tmp1, tmp2, N_EDGES);
    k_deg <<<gblocks, 256, 0, stream>>>(bcur1, tmp1, bcur2, tmp2, W1, b1, W2,
                                        cin, cout, tick1, nsA, hs0, ndv, U, V);
    k_agg1<<<gblocks, 256, 0, stream>>>(bcur1, tmp1, hs0, nsA, ndv, W1, b1,
                                        aggC, tick2, info);
    k_agg2<<<gblocks, 256, 0, stream>>>(bcur1, tmp1, info, ndv,
                                        aggA, aggB, aggMnI, aggMx, tick3, tickF,
                                        U, V, graph_ids, b2, pool, cnt, Wc, bc, out);
}